// Round 4
// baseline (1325.517 us; speedup 1.0000x reference)
//
#include <hip/hip_runtime.h>
#include <hip/hip_bf16.h>
#include <hip/hip_fp8.h>
#include <cstdint>
#include <cstddef>

// Problem constants (from reference)
#define E_ 8
#define H_ 2048
#define I_ 5632
#define N1_ (2 * I_)
#define G_ 128
#define T_ 256
#define RPE 256            // fixed rows per expert (= T_, exact worst case)
#define SLOTS (E_ * RPE)   // 2048

typedef __attribute__((ext_vector_type(4))) float f32x4;
typedef __attribute__((ext_vector_type(8))) __bf16 bf16x8;
typedef __attribute__((ext_vector_type(4))) int i32x4;

// Workspace layout (bytes). Total ~31.5 MB.
#define WS_CNT 0
#define WS_TOKEN 64
#define WS_GATE (64 + SLOTS * 4)
#define WS_A1 32768                    // SLOTS * H_ bf16 = 8 MB
#define WS_A2 (WS_A1 + SLOTS * H_ * 2) // SLOTS * I_ bf16 = 23 MB

__device__ __forceinline__ uint32_t pack_bf16x2(float a, float b) {
  union { float f; uint32_t u; } ua, ub;
  ua.f = a; ub.f = b;
  uint32_t ra = (ua.u + 0x7FFFu + ((ua.u >> 16) & 1u)) >> 16;         // RTNE bf16, low
  uint32_t rb = (ub.u + 0x7FFFu + ((ub.u >> 16) & 1u)) & 0xFFFF0000u; // high
  return ra | rb;
}

__device__ __forceinline__ float fp8_qdq1(float x) {
  x = fminf(fmaxf(x, -448.0f), 448.0f);
  __hip_fp8_e4m3 q(x);  // OCP e4m3fn on gfx950
  return (float)q;
}

// ---- wave-autonomous staging helpers (no barriers anywhere) ----------------
// Thread's weight patch: 4 rows (k = m*32 + kq4*4 + c) x 4 cols (gc4..gc4+4).
// wpt is pre-offset by kq4*4 rows + gc4 cols.
__device__ __forceinline__ void wissue4(const int* __restrict__ wpt, size_t ldN, int m,
                                        i32x4 wv[4]) {
#pragma unroll
  for (int c = 0; c < 4; ++c)
    wv[c] = __builtin_nontemporal_load(
        reinterpret_cast<const i32x4*>(wpt + ((size_t)m * 32 + c) * ldN));
}

// Dequant + RTNE-pack + 4x ds_write_b64 into the wave-private LDS slice.
// LDS layout per wave/buf: [kq(4)][col(32)][slot(8)] bf16, where element
// (kq,col,slot) = W[k0 + kq*8 + slot][gcol(col)] * scale.
__device__ __forceinline__ void wstage4(__hip_bfloat16 (*Btb)[32][8], int kqw, int c4, int s0,
                                        const i32x4 wv[4], f32x4 sc) {
#pragma unroll
  for (int i = 0; i < 4; ++i) {
    uint32_t p0 = pack_bf16x2((float)wv[0][i] * sc[i], (float)wv[1][i] * sc[i]);
    uint32_t p1 = pack_bf16x2((float)wv[2][i] * sc[i], (float)wv[3][i] * sc[i]);
    *(uint2*)&Btb[kqw][c4 + i][s0] = make_uint2(p0, p1);
  }
}

__device__ __forceinline__ void aissue8(const __hip_bfloat16* const aptr[8], int m, int nact,
                                        uint4 av[8]) {
#pragma unroll
  for (int mj = 0; mj < 8; ++mj)
    if (mj < nact) av[mj] = *(const uint4*)(aptr[mj] + (size_t)m * 32);
}

__device__ __forceinline__ void mfma2x8(const __hip_bfloat16 (*Btb)[32][8], int kq, int lm,
                                        int nact, const uint4 av[8], f32x4 acc[8][2]) {
#pragma unroll
  for (int f = 0; f < 2; ++f) {
    union { uint4 u; bf16x8 v; } bu;
    bu.u = *(const uint4*)&Btb[kq][f * 16 + lm][0];
#pragma unroll
    for (int mj = 0; mj < 8; ++mj)
      if (mj < nact) {
        union { uint4 u; bf16x8 v; } au;
        au.u = av[mj];
        acc[mj][f] = __builtin_amdgcn_mfma_f32_16x16x32_bf16(au.v, bu.v, acc[mj][f], 0, 0, 0);
      }
  }
}

// ---------------- routing: softmax top-2 -> fixed-capacity slot lists -------
__global__ void routing_kernel(const float* __restrict__ logits,
                               int* __restrict__ cnt,
                               int* __restrict__ token_of, float* __restrict__ gate_of) {
  __shared__ int s_cnt[E_];
  int t = threadIdx.x;  // one thread per token; blockDim.x == T_ == 256
  if (t < E_) s_cnt[t] = 0;
  __syncthreads();
  float l[E_];
#pragma unroll
  for (int e = 0; e < E_; e++) l[e] = logits[t * E_ + e];
  int i0 = 0;
#pragma unroll
  for (int e = 1; e < E_; e++) if (l[e] > l[i0]) i0 = e;  // ties -> lower idx
  int i1 = (i0 == 0) ? 1 : 0;
#pragma unroll
  for (int e = 0; e < E_; e++) if (e != i0 && l[e] > l[i1]) i1 = e;
  float g0 = 1.0f / (1.0f + expf(l[i1] - l[i0]));  // renormalized top-2 gates
  float g1 = 1.0f - g0;
  int s0 = atomicAdd(&s_cnt[i0], 1);
  int s1 = atomicAdd(&s_cnt[i1], 1);
  token_of[i0 * RPE + s0] = t;  gate_of[i0 * RPE + s0] = g0;
  token_of[i1 * RPE + s1] = t;  gate_of[i1 * RPE + s1] = g1;
  __syncthreads();
  if (t < E_) cnt[t] = s_cnt[t];
  for (int idx = t; idx < SLOTS; idx += 256) {
    int e = idx >> 8, r = idx & (RPE - 1);
    if (r >= s_cnt[e]) { token_of[idx] = 0; gate_of[idx] = 0.0f; }
  }
}

// ---------------- gather + fp8 qdq -> A1 (bf16, zero-padded rows) -----------
__global__ void gather_kernel(const float* __restrict__ hidden,
                              const float* __restrict__ is1,
                              const int* __restrict__ cnt,
                              const int* __restrict__ token_of,
                              __hip_bfloat16* __restrict__ A1) {
  int sg = blockIdx.x;
  int e = sg >> 8, r = sg & (RPE - 1);
  int c_n = cnt[e];
  int lim = ((c_n + 15) >> 4) << 4;   // rows beyond the last active chunk are never read
  if (r >= lim) return;
  bool pad = (r >= c_n);
  uint4 u;
  if (pad) {
    u.x = u.y = u.z = u.w = 0u;
  } else {
    int t = token_of[sg];
    float s1 = is1[e];
    const float4* hp = (const float4*)(hidden + (size_t)t * H_ + threadIdx.x * 8);
    float4 x0 = hp[0], x1 = hp[1];
    float q0 = fp8_qdq1(x0.x / s1), q1 = fp8_qdq1(x0.y / s1);
    float q2 = fp8_qdq1(x0.z / s1), q3 = fp8_qdq1(x0.w / s1);
    float q4 = fp8_qdq1(x1.x / s1), q5 = fp8_qdq1(x1.y / s1);
    float q6 = fp8_qdq1(x1.z / s1), q7 = fp8_qdq1(x1.w / s1);
    u.x = pack_bf16x2(q0, q1); u.y = pack_bf16x2(q2, q3);
    u.z = pack_bf16x2(q4, q5); u.w = pack_bf16x2(q6, q7);
  }
  ((uint4*)(A1 + (size_t)sg * H_))[threadIdx.x] = u;
}

// ---------------- fc1: ZERO-BARRIER wave-autonomous MFMA GEMM + SwiGLU ------
// Block = 4 independent waves. Wave w owns 16 up cols [j0+16w,+16) and the
// MATCHING 16 gate cols [I_+j0+16w,+16)  (j0 = bx*64), all M chunks (<=8/pass).
// Each wave stages its own weight tile into a wave-private LDS slice; the only
// synchronization is the wave's own vmcnt/lgkmcnt waits. No s_barrier at all.
__global__ __launch_bounds__(256, 2) void fc1_kernel(
    const int* __restrict__ w1, const float* __restrict__ w1s,
    const float* __restrict__ is1v, const float* __restrict__ is2v,
    const int* __restrict__ cnt,
    const __hip_bfloat16* __restrict__ A1, __hip_bfloat16* __restrict__ A2) {
  __shared__ __hip_bfloat16 Bt[4][2][4][32][8];  // 16 KB, wave-private slices
  const int e = blockIdx.y;
  const int j0 = blockIdx.x * 64;
  const int tid = threadIdx.x;
  const int wave = tid >> 6, lane = tid & 63;
  const int lm = lane & 15, kq = lane >> 4;
  // staging map: 4 cols x 4 k per lane, dwordx4 loads (128 B per 8 lanes)
  const int c4 = (lane & 7) * 4;       // logical col in [0,32)
  const int kq4 = lane >> 3;           // [0,8): 4-row group
  const int kqw = kq4 >> 1, s0 = (kq4 & 1) * 4;
  const int gc4 = (c4 < 16) ? (j0 + wave * 16 + c4) : (I_ + j0 + wave * 16 + (c4 - 16));
  const int* wpt = w1 + (size_t)e * H_ * N1_ + (size_t)(kq4 * 4) * N1_ + gc4;
  const float* spt = w1s + (size_t)e * (H_ / G_) * N1_ + gc4;
  const __hip_bfloat16* abase = A1 + (size_t)e * RPE * H_;
  auto& Btw = Bt[wave];

  const int C16 = (cnt[e] + 15) >> 4;
  const float s1 = is1v[e], s2 = is2v[e];
  __hip_bfloat16* a2base = A2 + (size_t)(e * RPE) * I_ + j0 + wave * 16;

  for (int mb = 0; mb < C16; mb += 8) {
    const int nact = (C16 - mb < 8) ? (C16 - mb) : 8;
    const __hip_bfloat16* aptr[8];
#pragma unroll
    for (int mj = 0; mj < 8; ++mj)
      aptr[mj] = abase + (size_t)((mb + mj) * 16 + lm) * H_ + kq * 8;

    f32x4 acc[8][2];
#pragma unroll
    for (int a = 0; a < 8; ++a)
#pragma unroll
      for (int b = 0; b < 2; ++b) acc[a][b] = (f32x4){0.f, 0.f, 0.f, 0.f};

    i32x4 wv0[4], wv1[4];
    uint4 av0[8], av1[8];
    f32x4 sc0 = *(const f32x4*)spt;  // group 0 (steps 0..3)
    f32x4 sc1 = sc0;
    wissue4(wpt, N1_, 0, wv0);
    wissue4(wpt, N1_, 1, wv1);
    aissue8(aptr, 0, nact, av1);
    wstage4(&Btw[0][0], kqw, c4, s0, wv0, sc0);

    for (int i = 0; i < 31; ++i) {
      const int m = 2 * i;
      // even half: compute step m (buf0, av1); prefetch step m+2 weights
      if (((m + 2) & 3) == 0) sc0 = *(const f32x4*)(spt + (size_t)((m + 2) >> 2) * N1_);
      wissue4(wpt, N1_, m + 2, wv0);
      aissue8(aptr, m + 1, nact, av0);
      mfma2x8(&Btw[0][0], kq, lm, nact, av1, acc);
      wstage4(&Btw[1][0], kqw, c4, s0, wv1, sc1);
      // odd half: compute step m+1 (buf1, av0); prefetch step m+3 weights
      if (((m + 3) & 3) == 1) sc1 = *(const f32x4*)(spt + (size_t)((m + 3) >> 2) * N1_);
      wissue4(wpt, N1_, m + 3, wv1);
      aissue8(aptr, m + 2, nact, av1);
      mfma2x8(&Btw[1][0], kq, lm, nact, av0, acc);
      wstage4(&Btw[0][0], kqw, c4, s0, wv0, sc0);
    }
    // peeled steps 62, 63
    aissue8(aptr, 63, nact, av0);
    mfma2x8(&Btw[0][0], kq, lm, nact, av1, acc);
    wstage4(&Btw[1][0], kqw, c4, s0, wv1, sc1);
    mfma2x8(&Btw[1][0], kq, lm, nact, av0, acc);

    // epilogue: SwiGLU in registers (up f=0, matching gate f=1, same lane)
#pragma unroll
    for (int mj = 0; mj < 8; ++mj) {
      if (mj < nact) {
        int mrow = (mb + mj) * 16 + kq * 4;
#pragma unroll
        for (int r = 0; r < 4; ++r) {
          float up = acc[mj][0][r] * s1;
          float gt = acc[mj][1][r] * s1;
          float h = up * (gt / (1.0f + expf(-gt)));  // up * silu(gate)
          float q = fp8_qdq1(h / s2);
          a2base[(size_t)(mrow + r) * I_ + lm] = __float2bfloat16(q);
        }
      }
    }
  }
}

// ---------------- fc2: same zero-barrier structure, split-K x4, scatter-add -
__global__ __launch_bounds__(256, 2) void fc2_kernel(
    const int* __restrict__ w2, const float* __restrict__ w2s,
    const float* __restrict__ is2v, const int* __restrict__ cnt,
    const int* __restrict__ token_of, const float* __restrict__ gate_of,
    const __hip_bfloat16* __restrict__ A2, float* __restrict__ out) {
  __shared__ __hip_bfloat16 Bt[4][2][4][32][8];  // 16 KB, wave-private slices
  const int e = blockIdx.y;
  const int n0 = blockIdx.x * 128;     // block covers 128 H cols; wave owns 32
  const int z = blockIdx.z;            // 4 k-slices of 1408 (44 steps)
  const int tid = threadIdx.x;
  const int wave = tid >> 6, lane = tid & 63;
  const int lm = lane & 15, kq = lane >> 4;
  const int c4 = (lane & 7) * 4;
  const int kq4 = lane >> 3;
  const int kqw = kq4 >> 1, s0 = (kq4 & 1) * 4;
  const int gc4 = n0 + wave * 32 + c4;
  const int* wpt = w2 + (size_t)e * I_ * H_ + (size_t)(z * 1408 + kq4 * 4) * H_ + gc4;
  const float* spt = w2s + (size_t)e * (I_ / G_) * H_ + gc4;
  const __hip_bfloat16* abase = A2 + (size_t)e * RPE * I_ + z * 1408;
  auto& Btw = Bt[wave];

  const int c_n = cnt[e];
  const int C16 = (c_n + 15) >> 4;
  const int z11 = z * 11;
  const float s2 = is2v[e];

  for (int mb = 0; mb < C16; mb += 8) {
    const int nact = (C16 - mb < 8) ? (C16 - mb) : 8;
    const __hip_bfloat16* aptr[8];
#pragma unroll
    for (int mj = 0; mj < 8; ++mj)
      aptr[mj] = abase + (size_t)((mb + mj) * 16 + lm) * I_ + kq * 8;

    f32x4 acc[8][2];
#pragma unroll
    for (int a = 0; a < 8; ++a)
#pragma unroll
      for (int b = 0; b < 2; ++b) acc[a][b] = (f32x4){0.f, 0.f, 0.f, 0.f};

    i32x4 wv0[4], wv1[4];
    uint4 av0[8], av1[8];
    f32x4 sc0 = *(const f32x4*)(spt + (size_t)z11 * H_);
    f32x4 sc1 = sc0;
    wissue4(wpt, H_, 0, wv0);
    wissue4(wpt, H_, 1, wv1);
    aissue8(aptr, 0, nact, av1);
    wstage4(&Btw[0][0], kqw, c4, s0, wv0, sc0);

    for (int i = 0; i < 21; ++i) {
      const int m = 2 * i;
      if (((m + 2) & 3) == 0)
        sc0 = *(const f32x4*)(spt + (size_t)(z11 + ((m + 2) >> 2)) * H_);
      wissue4(wpt, H_, m + 2, wv0);
      aissue8(aptr, m + 1, nact, av0);
      mfma2x8(&Btw[0][0], kq, lm, nact, av1, acc);
      wstage4(&Btw[1][0], kqw, c4, s0, wv1, sc1);
      if (((m + 3) & 3) == 1)
        sc1 = *(const f32x4*)(spt + (size_t)(z11 + ((m + 3) >> 2)) * H_);
      wissue4(wpt, H_, m + 3, wv1);
      aissue8(aptr, m + 2, nact, av1);
      mfma2x8(&Btw[1][0], kq, lm, nact, av0, acc);
      wstage4(&Btw[0][0], kqw, c4, s0, wv0, sc0);
    }
    // peeled steps 42, 43
    aissue8(aptr, 43, nact, av0);
    mfma2x8(&Btw[0][0], kq, lm, nact, av1, acc);
    wstage4(&Btw[1][0], kqw, c4, s0, wv1, sc1);
    mfma2x8(&Btw[1][0], kq, lm, nact, av0, acc);

    // epilogue: gated atomic scatter-add (wave-private columns)
#pragma unroll
    for (int mj = 0; mj < 8; ++mj) {
      if (mj < nact) {
        int sl0 = (mb + mj) * 16 + kq * 4;
#pragma unroll
        for (int r = 0; r < 4; ++r) {
          int slot = sl0 + r;
          if (slot < c_n) {
            int t = token_of[e * RPE + slot];
            float gv = gate_of[e * RPE + slot] * s2;
#pragma unroll
            for (int f = 0; f < 2; ++f)
              atomicAdd(out + (size_t)t * H_ + n0 + wave * 32 + f * 16 + lm,
                        acc[mj][f][r] * gv);
          }
        }
      }
    }
  }
}

extern "C" void kernel_launch(void* const* d_in, const int* in_sizes, int n_in,
                              void* d_out, int out_size, void* d_ws, size_t ws_size,
                              hipStream_t stream) {
  const float* hidden = (const float*)d_in[0];
  const float* logits = (const float*)d_in[1];
  const int* w1 = (const int*)d_in[2];
  const int* w2 = (const int*)d_in[3];
  const float* w1s = (const float*)d_in[4];
  const float* w2s = (const float*)d_in[5];
  const float* is1 = (const float*)d_in[6];
  const float* is2 = (const float*)d_in[7];
  float* out = (float*)d_out;
  char* ws = (char*)d_ws;
  int* cnt = (int*)(ws + WS_CNT);
  int* token_of = (int*)(ws + WS_TOKEN);
  float* gate_of = (float*)(ws + WS_GATE);
  __hip_bfloat16* A1 = (__hip_bfloat16*)(ws + WS_A1);
  __hip_bfloat16* A2 = (__hip_bfloat16*)(ws + WS_A2);

  hipMemsetAsync(d_out, 0, (size_t)T_ * H_ * sizeof(float), stream);
  routing_kernel<<<1, 256, 0, stream>>>(logits, cnt, token_of, gate_of);
  gather_kernel<<<SLOTS, 256, 0, stream>>>(hidden, is1, cnt, token_of, A1);
  fc1_kernel<<<dim3(I_ / 64, E_), 256, 0, stream>>>(w1, w1s, is1, is2, cnt, A1, A2);
  fc2_kernel<<<dim3(H_ / 128, E_, 4), 256, 0, stream>>>(w2, w2s, is2, cnt, token_of,
                                                        gate_of, A2, out);
}

// Round 6
// 1268.580 us; speedup vs baseline: 1.0449x; 1.0449x over previous
//
#include <hip/hip_runtime.h>
#include <hip/hip_bf16.h>
#include <hip/hip_fp8.h>
#include <cstdint>
#include <cstddef>

// Problem constants (from reference)
#define E_ 8
#define H_ 2048
#define I_ 5632
#define N1_ (2 * I_)
#define G_ 128
#define T_ 256
#define RPE 256            // fixed rows per expert (= T_, exact worst case)
#define SLOTS (E_ * RPE)   // 2048

typedef __attribute__((ext_vector_type(4))) float f32x4;
typedef __attribute__((ext_vector_type(8))) __bf16 bf16x8;
typedef __attribute__((ext_vector_type(4))) int i32x4;

// Workspace layout (bytes). Total ~31.5 MB.
#define WS_CNT 0
#define WS_TOKEN 64
#define WS_GATE (64 + SLOTS * 4)
#define WS_A1 32768                    // SLOTS * H_ bf16 = 8 MB
#define WS_A2 (WS_A1 + SLOTS * H_ * 2) // SLOTS * I_ bf16 = 23 MB

__device__ __forceinline__ uint32_t pack_bf16x2(float a, float b) {
  union { float f; uint32_t u; } ua, ub;
  ua.f = a; ub.f = b;
  uint32_t ra = (ua.u + 0x7FFFu + ((ua.u >> 16) & 1u)) >> 16;         // RTNE bf16, low
  uint32_t rb = (ub.u + 0x7FFFu + ((ub.u >> 16) & 1u)) & 0xFFFF0000u; // high
  return ra | rb;
}

__device__ __forceinline__ float fp8_qdq1(float x) {
  x = fminf(fmaxf(x, -448.0f), 448.0f);
  __hip_fp8_e4m3 q(x);  // OCP e4m3fn on gfx950
  return (float)q;
}

// Workgroup barrier WITHOUT vmcnt drain: orders LDS traffic (lgkmcnt) only, so
// in-flight global prefetches (weights, A-frags) survive the barrier (T4).
__device__ __forceinline__ void block_sync_nodrain() {
  __builtin_amdgcn_sched_barrier(0);
  asm volatile("s_waitcnt lgkmcnt(0)" ::: "memory");
  __builtin_amdgcn_s_barrier();
  __builtin_amdgcn_sched_barrier(0);
}

// ---- staging helpers -------------------------------------------------------
// Thread's weight patch per k-step: 2 rows (k = m*32 + r2*2 + j) x 4 cols.
// wpt pre-offset by r2*2 rows + gc4 col. Two dwordx4 loads (32 B/thread).
__device__ __forceinline__ void wissue(const int* __restrict__ wpt, size_t ldN, int m,
                                       i32x4 wv[2]) {
  wv[0] = __builtin_nontemporal_load(
      reinterpret_cast<const i32x4*>(wpt + ((size_t)m * 32) * ldN));
  wv[1] = __builtin_nontemporal_load(
      reinterpret_cast<const i32x4*>(wpt + ((size_t)m * 32 + 1) * ldN));
}

// Dequant + RTNE-pack + 4x ds_write_b32. LDS layout (same as prior rounds):
// Bt[kq][n(64)][slot(8)] = bf16 of W[klocal = kq*8 + slot][gcol(n)] * scale.
// Thread writes slots (s0, s0+1) of cols c4..c4+3 at kq = kqs.
__device__ __forceinline__ void wstage(__hip_bfloat16 (*Btb)[64][8], int kqs, int c4, int s0,
                                       const i32x4 wv[2], f32x4 sc) {
#pragma unroll
  for (int i = 0; i < 4; ++i) {
    uint32_t p = pack_bf16x2((float)wv[0][i] * sc[i], (float)wv[1][i] * sc[i]);
    *(uint32_t*)&Btb[kqs][c4 + i][s0] = p;
  }
}

__device__ __forceinline__ void aissue(const __hip_bfloat16* const aptr[4], int m, int nact,
                                       uint4 av[4]) {
#pragma unroll
  for (int mj = 0; mj < 4; ++mj)
    if (mj < nact) av[mj] = *(const uint4*)(aptr[mj] + (size_t)m * 32);
}

__device__ __forceinline__ void do_mfma(const __hip_bfloat16 (*Btb)[64][8], int kq, int lm,
                                        int nact, const uint4 afr[4], f32x4 acc[4][4]) {
#pragma unroll
  for (int f = 0; f < 4; ++f) {
    union { uint4 u; bf16x8 v; } bu;
    bu.u = *(const uint4*)&Btb[kq][f * 16 + lm][0];
#pragma unroll
    for (int mj = 0; mj < 4; ++mj)
      if (mj < nact) {
        union { uint4 u; bf16x8 v; } au;
        au.u = afr[mj];
        acc[mj][f] = __builtin_amdgcn_mfma_f32_16x16x32_bf16(au.v, bu.v, acc[mj][f], 0, 0, 0);
      }
  }
}

// ---------------- routing: softmax top-2 -> fixed-capacity slot lists -------
__global__ void routing_kernel(const float* __restrict__ logits,
                               int* __restrict__ cnt,
                               int* __restrict__ token_of, float* __restrict__ gate_of) {
  __shared__ int s_cnt[E_];
  int t = threadIdx.x;  // one thread per token; blockDim.x == T_ == 256
  if (t < E_) s_cnt[t] = 0;
  __syncthreads();
  float l[E_];
#pragma unroll
  for (int e = 0; e < E_; e++) l[e] = logits[t * E_ + e];
  int i0 = 0;
#pragma unroll
  for (int e = 1; e < E_; e++) if (l[e] > l[i0]) i0 = e;  // ties -> lower idx
  int i1 = (i0 == 0) ? 1 : 0;
#pragma unroll
  for (int e = 0; e < E_; e++) if (e != i0 && l[e] > l[i1]) i1 = e;
  float g0 = 1.0f / (1.0f + expf(l[i1] - l[i0]));  // renormalized top-2 gates
  float g1 = 1.0f - g0;
  int s0 = atomicAdd(&s_cnt[i0], 1);
  int s1 = atomicAdd(&s_cnt[i1], 1);
  token_of[i0 * RPE + s0] = t;  gate_of[i0 * RPE + s0] = g0;
  token_of[i1 * RPE + s1] = t;  gate_of[i1 * RPE + s1] = g1;
  __syncthreads();
  if (t < E_) cnt[t] = s_cnt[t];
  for (int idx = t; idx < SLOTS; idx += 256) {
    int e = idx >> 8, r = idx & (RPE - 1);
    if (r >= s_cnt[e]) { token_of[idx] = 0; gate_of[idx] = 0.0f; }
  }
}

// ---------------- gather + fp8 qdq -> A1 (bf16, zero-padded rows) -----------
__global__ void gather_kernel(const float* __restrict__ hidden,
                              const float* __restrict__ is1,
                              const int* __restrict__ cnt,
                              const int* __restrict__ token_of,
                              __hip_bfloat16* __restrict__ A1) {
  int sg = blockIdx.x;
  int e = sg >> 8, r = sg & (RPE - 1);
  int c_n = cnt[e];
  int lim = ((c_n + 15) >> 4) << 4;   // rows beyond the last active chunk are never read
  if (r >= lim) return;
  bool pad = (r >= c_n);
  uint4 u;
  if (pad) {
    u.x = u.y = u.z = u.w = 0u;
  } else {
    int t = token_of[sg];
    float s1 = is1[e];
    const float4* hp = (const float4*)(hidden + (size_t)t * H_ + threadIdx.x * 8);
    float4 x0 = hp[0], x1 = hp[1];
    float q0 = fp8_qdq1(x0.x / s1), q1 = fp8_qdq1(x0.y / s1);
    float q2 = fp8_qdq1(x0.z / s1), q3 = fp8_qdq1(x0.w / s1);
    float q4 = fp8_qdq1(x1.x / s1), q5 = fp8_qdq1(x1.y / s1);
    float q6 = fp8_qdq1(x1.z / s1), q7 = fp8_qdq1(x1.w / s1);
    u.x = pack_bf16x2(q0, q1); u.y = pack_bf16x2(q2, q3);
    u.z = pack_bf16x2(q4, q5); u.w = pack_bf16x2(q6, q7);
  }
  ((uint4*)(A1 + (size_t)sg * H_))[threadIdx.x] = u;
}

// ---------------- fc1: depth-4 pipelined MFMA GEMM + fused SwiGLU -----------
// Block = 4 waves (R3 structure). Staging: thread t owns 4 cols ((t&15)*4) x
// 2 rows (r2=t>>4), 2x dwordx4 per step. Unroll-4 k-loop with 4 named weight
// reg sets (wvA..wvD): every load has 3 k-steps of slack before its wstage,
// and the no-drain barrier keeps loads in flight across syncs.
__global__ __launch_bounds__(256) void fc1_kernel(
    const int* __restrict__ w1, const float* __restrict__ w1s,
    const float* __restrict__ is1v, const float* __restrict__ is2v,
    const int* __restrict__ cnt,
    const __hip_bfloat16* __restrict__ A1, __hip_bfloat16* __restrict__ A2) {
  __shared__ __hip_bfloat16 Bt[2][4][64][8];  // 8 KB
  const int e = blockIdx.y;
  const int j0 = blockIdx.x * 32;
  const int tid = threadIdx.x;
  const int wave = tid >> 6, lane = tid & 63;
  const int lm = lane & 15, kq = lane >> 4;
  // staging map
  const int c4 = (tid & 15) * 4;      // logical col in [0,64)
  const int r2 = tid >> 4;            // [0,16): 2-row group (rows r2*2, r2*2+1)
  const int kqs = r2 >> 2, s0 = (r2 * 2) & 7;
  const int gc4 = (c4 < 32) ? (j0 + c4) : (I_ + j0 + (c4 - 32));
  const int* wpt = w1 + (size_t)e * H_ * N1_ + (size_t)(r2 * 2) * N1_ + gc4;
  const float* spt = w1s + (size_t)e * (H_ / G_) * N1_ + gc4;
  const __hip_bfloat16* abase = A1 + (size_t)e * RPE * H_;

  const int C16 = (cnt[e] + 15) >> 4;
  int nact = (C16 - wave + 3) >> 2;   // interleaved chunk map: wave w owns w,w+4,w+8,w+12
  if (nact < 0) nact = 0;

  f32x4 acc[4][4];
#pragma unroll
  for (int a = 0; a < 4; a++)
#pragma unroll
    for (int b = 0; b < 4; b++) acc[a][b] = (f32x4){0.f, 0.f, 0.f, 0.f};

  const __hip_bfloat16* aptr[4];
#pragma unroll
  for (int mj = 0; mj < 4; mj++)
    aptr[mj] = abase + (size_t)((mj * 4 + wave) * 16 + lm) * H_ + kq * 8;

  // prologue: wvA..wvD hold steps 0..3; stage step 0; A for step 0
  i32x4 wvA[2], wvB[2], wvC[2], wvD[2];
  uint4 av0[4], av1[4];
  f32x4 scCur = *(const f32x4*)spt;   // group 0
  wissue(wpt, N1_, 0, wvA);
  wissue(wpt, N1_, 1, wvB);
  wissue(wpt, N1_, 2, wvC);
  wissue(wpt, N1_, 3, wvD);
  aissue(aptr, 0, nact, av1);
  wstage(Bt[0], kqs, c4, s0, wvA, scCur);
  block_sync_nodrain();

  for (int it = 0; it < 16; ++it) {
    const int m = it * 4;
    f32x4 scN = scCur;
    if (it + 1 < 16) scN = *(const f32x4*)(spt + (size_t)(it + 1) * N1_);
    // sub0: compute m (buf0, av1); reissue wvA -> m+4
    if (m + 4 < 64) wissue(wpt, N1_, m + 4, wvA);
    if (m + 1 < 64) aissue(aptr, m + 1, nact, av0);
    do_mfma(Bt[0], kq, lm, nact, av1, acc);
    wstage(Bt[1], kqs, c4, s0, wvB, scCur);   // step m+1
    block_sync_nodrain();
    // sub1: compute m+1 (buf1, av0); reissue wvB -> m+5
    if (m + 5 < 64) wissue(wpt, N1_, m + 5, wvB);
    if (m + 2 < 64) aissue(aptr, m + 2, nact, av1);
    do_mfma(Bt[1], kq, lm, nact, av0, acc);
    wstage(Bt[0], kqs, c4, s0, wvC, scCur);   // step m+2
    block_sync_nodrain();
    // sub2: compute m+2 (buf0, av1); reissue wvC -> m+6
    if (m + 6 < 64) wissue(wpt, N1_, m + 6, wvC);
    if (m + 3 < 64) aissue(aptr, m + 3, nact, av0);
    do_mfma(Bt[0], kq, lm, nact, av1, acc);
    wstage(Bt[1], kqs, c4, s0, wvD, scCur);   // step m+3
    block_sync_nodrain();
    // sub3: compute m+3 (buf1, av0); reissue wvD -> m+7
    if (m + 7 < 64) wissue(wpt, N1_, m + 7, wvD);
    if (m + 4 < 64) aissue(aptr, m + 4, nact, av1);
    do_mfma(Bt[1], kq, lm, nact, av0, acc);
    if (m + 4 < 64) wstage(Bt[0], kqs, c4, s0, wvA, scN);  // step m+4
    block_sync_nodrain();
    scCur = scN;
  }

  // epilogue: SwiGLU in registers (wave holds matching up f and gate f+2 cols)
  const float s1 = is1v[e], s2 = is2v[e];
  __hip_bfloat16* a2base = A2 + (size_t)(e * RPE) * I_ + j0;
#pragma unroll
  for (int mj = 0; mj < 4; mj++) {
    if (mj < nact) {
      int mrow = (mj * 4 + wave) * 16 + kq * 4;
#pragma unroll
      for (int r = 0; r < 4; r++) {
#pragma unroll
        for (int f = 0; f < 2; f++) {
          float up = acc[mj][f][r] * s1;
          float gt = acc[mj][f + 2][r] * s1;
          float h = up * (gt / (1.0f + expf(-gt)));  // up * silu(gate)
          float q = fp8_qdq1(h / s2);
          a2base[(size_t)(mrow + r) * I_ + f * 16 + lm] = __float2bfloat16(q);
        }
      }
    }
  }
}

// ---------------- fc2: same structure, split-K x4, atomic scatter-add -------
__global__ __launch_bounds__(256) void fc2_kernel(
    const int* __restrict__ w2, const float* __restrict__ w2s,
    const float* __restrict__ is2v, const int* __restrict__ cnt,
    const int* __restrict__ token_of, const float* __restrict__ gate_of,
    const __hip_bfloat16* __restrict__ A2, float* __restrict__ out) {
  __shared__ __hip_bfloat16 Bt[2][4][64][8];  // 8 KB
  const int e = blockIdx.y;
  const int n0 = blockIdx.x * 64;
  const int z = blockIdx.z;       // 4 k-slices of 1408 (44 steps of 32)
  const int tid = threadIdx.x;
  const int wave = tid >> 6, lane = tid & 63;
  const int lm = lane & 15, kq = lane >> 4;
  const int c4 = (tid & 15) * 4;
  const int r2 = tid >> 4;
  const int kqs = r2 >> 2, s0 = (r2 * 2) & 7;
  const int gc4 = n0 + c4;
  const int z11 = z * 11;
  const int* wpt = w2 + (size_t)e * I_ * H_ + (size_t)(z * 1408 + r2 * 2) * H_ + gc4;
  const float* spt = w2s + (size_t)e * (I_ / G_) * H_ + gc4;
  const __hip_bfloat16* abase = A2 + (size_t)e * RPE * I_ + z * 1408;

  const int c_n = cnt[e];
  const int C16 = (c_n + 15) >> 4;
  int nact = (C16 - wave + 3) >> 2;  // same interleaved chunk map as fc1
  if (nact < 0) nact = 0;

  f32x4 acc[4][4];
#pragma unroll
  for (int a = 0; a < 4; a++)
#pragma unroll
    for (int b = 0; b < 4; b++) acc[a][b] = (f32x4){0.f, 0.f, 0.f, 0.f};

  const __hip_bfloat16* aptr[4];
#pragma unroll
  for (int mj = 0; mj < 4; mj++)
    aptr[mj] = abase + (size_t)((mj * 4 + wave) * 16 + lm) * I_ + kq * 8;

  i32x4 wvA[2], wvB[2], wvC[2], wvD[2];
  uint4 av0[4], av1[4];
  f32x4 scCur = *(const f32x4*)(spt + (size_t)z11 * H_);
  wissue(wpt, H_, 0, wvA);
  wissue(wpt, H_, 1, wvB);
  wissue(wpt, H_, 2, wvC);
  wissue(wpt, H_, 3, wvD);
  aissue(aptr, 0, nact, av1);
  wstage(Bt[0], kqs, c4, s0, wvA, scCur);
  block_sync_nodrain();

  for (int it = 0; it < 11; ++it) {
    const int m = it * 4;
    f32x4 scN = scCur;
    if (it + 1 < 11) scN = *(const f32x4*)(spt + (size_t)(z11 + it + 1) * H_);
    if (m + 4 < 44) wissue(wpt, H_, m + 4, wvA);
    if (m + 1 < 44) aissue(aptr, m + 1, nact, av0);
    do_mfma(Bt[0], kq, lm, nact, av1, acc);
    wstage(Bt[1], kqs, c4, s0, wvB, scCur);
    block_sync_nodrain();
    if (m + 5 < 44) wissue(wpt, H_, m + 5, wvB);
    if (m + 2 < 44) aissue(aptr, m + 2, nact, av1);
    do_mfma(Bt[1], kq, lm, nact, av0, acc);
    wstage(Bt[0], kqs, c4, s0, wvC, scCur);
    block_sync_nodrain();
    if (m + 6 < 44) wissue(wpt, H_, m + 6, wvC);
    if (m + 3 < 44) aissue(aptr, m + 3, nact, av0);
    do_mfma(Bt[0], kq, lm, nact, av1, acc);
    wstage(Bt[1], kqs, c4, s0, wvD, scCur);
    block_sync_nodrain();
    if (m + 7 < 44) wissue(wpt, H_, m + 7, wvD);
    if (m + 4 < 44) aissue(aptr, m + 4, nact, av1);
    do_mfma(Bt[1], kq, lm, nact, av0, acc);
    if (m + 4 < 44) wstage(Bt[0], kqs, c4, s0, wvA, scN);
    block_sync_nodrain();
    scCur = scN;
  }

  const float s2 = is2v[e];
#pragma unroll
  for (int mj = 0; mj < 4; mj++) {
    if (mj < nact) {
      int sl0 = (mj * 4 + wave) * 16 + kq * 4;
#pragma unroll
      for (int r = 0; r < 4; r++) {
        int slot = sl0 + r;
        if (slot < c_n) {
          int t = token_of[e * RPE + slot];
          float gv = gate_of[e * RPE + slot] * s2;
#pragma unroll
          for (int f = 0; f < 4; f++)
            atomicAdd(out + (size_t)t * H_ + n0 + f * 16 + lm, acc[mj][f][r] * gv);
        }
      }
    }
  }
}

extern "C" void kernel_launch(void* const* d_in, const int* in_sizes, int n_in,
                              void* d_out, int out_size, void* d_ws, size_t ws_size,
                              hipStream_t stream) {
  const float* hidden = (const float*)d_in[0];
  const float* logits = (const float*)d_in[1];
  const int* w1 = (const int*)d_in[2];
  const int* w2 = (const int*)d_in[3];
  const float* w1s = (const float*)d_in[4];
  const float* w2s = (const float*)d_in[5];
  const float* is1 = (const float*)d_in[6];
  const float* is2 = (const float*)d_in[7];
  float* out = (float*)d_out;
  char* ws = (char*)d_ws;
  int* cnt = (int*)(ws + WS_CNT);
  int* token_of = (int*)(ws + WS_TOKEN);
  float* gate_of = (float*)(ws + WS_GATE);
  __hip_bfloat16* A1 = (__hip_bfloat16*)(ws + WS_A1);
  __hip_bfloat16* A2 = (__hip_bfloat16*)(ws + WS_A2);

  hipMemsetAsync(d_out, 0, (size_t)T_ * H_ * sizeof(float), stream);
  routing_kernel<<<1, 256, 0, stream>>>(logits, cnt, token_of, gate_of);
  gather_kernel<<<SLOTS, 256, 0, stream>>>(hidden, is1, cnt, token_of, A1);
  fc1_kernel<<<dim3(I_ / 32, E_), 256, 0, stream>>>(w1, w1s, is1, is2, cnt, A1, A2);
  fc2_kernel<<<dim3(H_ / 64, E_, 4), 256, 0, stream>>>(w2, w2s, is2, cnt, token_of,
                                                       gate_of, A2, out);
}